// Round 6
// baseline (223.447 us; speedup 1.0000x reference)
//
#include <hip/hip_runtime.h>
#include <hip/hip_bf16.h>

#define N 4096
#define IN_DIM 256
#define HID 64
#define NHEADS 4
#define OUT_DIM 128
#define LOG2E 1.44269504088896340736f
// ---- R6 PROBE: every kernel repeats its full computation REP times with
// identical (idempotent) writes. Purpose: double each dispatch's duration so
// kernels >=21us real cross the 41us harness-fill threshold and surface in
// rocprof top-5 WITH counters. dur_us delta vs R5 == exact total kernel time.
#define REP 2

typedef __attribute__((ext_vector_type(8))) short bf16x8;
typedef __attribute__((ext_vector_type(4))) float f32x4;

// Two-term bf16 split: v ~= hi + lo with |err| ~ 2^-17 |v|.
__device__ __forceinline__ ushort2 bsplit(float v) {
    const ushort h = __hip_bfloat16_raw(__float2bfloat16(v)).x;
    const float vh = __uint_as_float((unsigned)h << 16);
    const ushort l = __hip_bfloat16_raw(__float2bfloat16(v - vh)).x;
    return make_ushort2(h, l);
}

// ---------------------------------------------------------------------------
// prep_kernel = gemm1-MFMA (blocks 0..255) + mask pack (blocks 256..1279).
// ---------------------------------------------------------------------------
__global__ __launch_bounds__(256, 4) void prep_kernel(
        const float* __restrict__ x, const float* __restrict__ W,
        const float* __restrict__ a, const int* __restrict__ adj,
        __hip_bfloat16* __restrict__ WhB,
        float* __restrict__ f1, float* __restrict__ f2,
        unsigned* __restrict__ maskT) {
    const int t = threadIdx.x;
    if (blockIdx.x < 256) {
        // ---------------- gemm1 via MFMA ----------------
        const int h = t >> 6, lane = t & 63, m = lane & 15, quad = lane >> 4;
        const int i0 = blockIdx.x * 16;
        const float* xrow = x + (size_t)(i0 + m) * IN_DIM;
        const float* Wp = W + (size_t)h * IN_DIM * HID;
        for (int rep = 0; rep < REP; rep++) {
        const f32x4 zero = {0.f, 0.f, 0.f, 0.f};
        f32x4 acc[4] = {zero, zero, zero, zero};
        for (int ks = 0; ks < 8; ks++) {
            const int kb = ks * 32 + quad * 8;
            const float4 xa = *(const float4*)(xrow + kb);
            const float4 xb = *(const float4*)(xrow + kb + 4);
            const float xf[8] = {xa.x, xa.y, xa.z, xa.w, xb.x, xb.y, xb.z, xb.w};
            bf16x8 xh, xl;
#pragma unroll
            for (int e = 0; e < 8; e++) {
                const ushort2 s = bsplit(xf[e]);
                xh[e] = (short)s.x; xl[e] = (short)s.y;
            }
#pragma unroll
            for (int ct = 0; ct < 4; ct++) {
                bf16x8 wh, wl;
#pragma unroll
                for (int e = 0; e < 8; e++) {
                    const ushort2 s =
                        bsplit(Wp[(size_t)(kb + e) * HID + ct * 16 + m]);
                    wh[e] = (short)s.x; wl[e] = (short)s.y;
                }
                acc[ct] = __builtin_amdgcn_mfma_f32_16x16x32_bf16(
                    xh, wh, acc[ct], 0, 0, 0);
                acc[ct] = __builtin_amdgcn_mfma_f32_16x16x32_bf16(
                    xl, wh, acc[ct], 0, 0, 0);
                acc[ct] = __builtin_amdgcn_mfma_f32_16x16x32_bf16(
                    xh, wl, acc[ct], 0, 0, 0);
            }
        }
        // ---- WhB1 frag store: j = i0+quad*4+r, c = ct*16+m ----
        const int jblk = i0 >> 5, jb2 = (i0 >> 4) & 1;
#pragma unroll
        for (int ct = 0; ct < 4; ct++) {
#pragma unroll
            for (int r = 0; r < 4; r++) {
                const int jo = quad * 4 + r;
                const int lane_idx = m + 16 * (2 * jb2 + (jo >> 3));
                WhB[((((size_t)h * (N / 32) + jblk) * 4 + ct) * 64 + lane_idx) *
                        8 + (jo & 7)] = __float2bfloat16(acc[ct][r]);
            }
        }
        // ---- f1/f2 ----
        float av1[4], av2[4];
#pragma unroll
        for (int ct = 0; ct < 4; ct++) {
            av1[ct] = a[h * 2 * HID + ct * 16 + m];
            av2[ct] = a[h * 2 * HID + HID + ct * 16 + m];
        }
        float s1[4], s2[4];
#pragma unroll
        for (int r = 0; r < 4; r++) {
            s1[r] = 0.f; s2[r] = 0.f;
#pragma unroll
            for (int ct = 0; ct < 4; ct++) {
                s1[r] += acc[ct][r] * av1[ct];
                s2[r] += acc[ct][r] * av2[ct];
            }
        }
#pragma unroll
        for (int mm = 8; mm > 0; mm >>= 1) {
#pragma unroll
            for (int r = 0; r < 4; r++) {
                s1[r] += __shfl_xor(s1[r], mm, 64);
                s2[r] += __shfl_xor(s2[r], mm, 64);
            }
        }
        if (m == 0) {
#pragma unroll
            for (int r = 0; r < 4; r++) {
                f1[(size_t)h * N + i0 + quad * 4 + r] = s1[r] * LOG2E;
                f2[(size_t)h * N + i0 + quad * 4 + r] = s2[r] * LOG2E;
            }
        }
        }  // rep
    } else {
        // ---------------- mask pack (bit-spread, verified R6) ----------------
        const int lane = t & 63, w = t >> 6;
        const int i = (blockIdx.x - 256) * 4 + w;      // one row per wave
        const int4* arow = (const int4*)(adj + (size_t)i * N);
        for (int rep = 0; rep < REP; rep++) {
        for (int jb = 0; jb < N / 256; jb++) {
            const int4 a4 = arow[jb * 64 + lane];
            unsigned long long bal[4];
            bal[0] = __ballot(a4.x > 0);
            bal[1] = __ballot(a4.y > 0);
            bal[2] = __ballot(a4.z > 0);
            bal[3] = __ballot(a4.w > 0);
            if (lane < 8) {
                unsigned word = 0;
#pragma unroll
                for (int e = 0; e < 4; e++) {
                    unsigned xv = (unsigned)(bal[e] >> (8 * lane)) & 0xFFu;
                    xv = (xv | (xv << 12)) & 0x000F000Fu;
                    xv = (xv | (xv << 6))  & 0x03030303u;
                    xv = (xv | (xv << 3))  & 0x11111111u;
                    word |= xv << e;
                }
                maskT[(size_t)(jb * 8 + lane) * N + i] = word;
            }
        }
        }  // rep
    }
}

// ---------------------------------------------------------------------------
// Fused attention layer (verified R7/R8 structure), REP-doubled for probe.
// L1: HEADS=4, DSL=1, MW=2, G=8 -> grid (128,4)=512 blocks, 512 thr.
// L2: HEADS=1, DSL=2, MW=1, G=8 -> grid (256,2)=512 blocks, 512 thr.
// ---------------------------------------------------------------------------
template <int HEADS, int D, int DSL, int G, int MW>
__global__ __launch_bounds__(G * 64, 4) void attn_fused(
        const unsigned* __restrict__ maskT,             // [N/32][N]
        const __hip_bfloat16* __restrict__ WhB,          // [H][N/32][D/16][64][8]
        const float* __restrict__ f1g, const float* __restrict__ f2g,
        float* __restrict__ outp) {
    constexpr int CTtot = D / 16;
    constexpr int CTT = CTtot / DSL;
    constexpr int CC = (D == 64) ? 1 : 2;
    constexpr int KSTEPS = N / (32 * G);
    __shared__ float sh[MW * G * 16 * CC * 17];
    __shared__ float dsh[MW * G * 16];
    const int t = threadIdx.x;
    const int g = t >> 6, lane = t & 63;
    const int m = lane & 15, quad = lane >> 4;
    const int h = blockIdx.y / DSL, slc = blockIdx.y % DSL;
    const int i0 = blockIdx.x * (16 * MW);

    float f1v[MW];
#pragma unroll
    for (int mw = 0; mw < MW; mw++)
        f1v[mw] = f1g[(size_t)h * N + i0 + mw * 16 + m];
    const float* f2p = f2g + (size_t)h * N;
    const bf16x8* whb = (const bf16x8*)WhB + (size_t)h * (N / 32) * CTtot * 64;

    const short one_bf = (short)0x3F80;
    const bf16x8 ones = {one_bf, one_bf, one_bf, one_bf,
                         one_bf, one_bf, one_bf, one_bf};

    unsigned mwrd[2][MW];
    float f2v[2][8];
    auto stage_mf = [&](int ks, int b) {
        const int j0 = g * (N / G) + ks * 32;
        const int jw = j0 >> 5;
#pragma unroll
        for (int mw = 0; mw < MW; mw++)
            mwrd[b][mw] = maskT[(size_t)jw * N + i0 + mw * 16 + m];
        const float4 lo = *(const float4*)(f2p + j0 + quad * 8);
        const float4 hi = *(const float4*)(f2p + j0 + quad * 8 + 4);
        f2v[b][0] = lo.x; f2v[b][1] = lo.y; f2v[b][2] = lo.z; f2v[b][3] = lo.w;
        f2v[b][4] = hi.x; f2v[b][5] = hi.y; f2v[b][6] = hi.z; f2v[b][7] = hi.w;
    };

    for (int rep = 0; rep < REP; rep++) {
    const f32x4 zero = {0.f, 0.f, 0.f, 0.f};
    f32x4 acc[MW][CTT];
    f32x4 sac[MW];
#pragma unroll
    for (int mw = 0; mw < MW; mw++) {
        sac[mw] = zero;
#pragma unroll
        for (int ct = 0; ct < CTT; ct++) acc[mw][ct] = zero;
    }
    stage_mf(0, 0);
#pragma unroll 2
    for (int ks = 0; ks < KSTEPS; ks++) {
        const int cur = ks & 1;
        const int jwc = (g * (N / G) + ks * 32) >> 5;
        const bf16x8* bp = whb + ((size_t)jwc * CTtot + slc * CTT) * 64 + lane;
        bf16x8 bfrag[CTT];
#pragma unroll
        for (int ct = 0; ct < CTT; ct++) bfrag[ct] = bp[ct * 64];
        if (ks + 1 < KSTEPS) stage_mf(ks + 1, cur ^ 1);
        // ---- P-gen ----
        bf16x8 afr[MW];
#pragma unroll
        for (int mw = 0; mw < MW; mw++) {
            const unsigned mword = mwrd[cur][mw] >> (quad * 8);
            float p[8];
#pragma unroll
            for (int e = 0; e < 8; e++) {
                const float tt = f1v[mw] + f2v[cur][e];
                const float lr = fmaxf(tt, 0.5f * tt);        // LeakyReLU(0.5)
                const float pe = __builtin_amdgcn_exp2f(lr);  // log2e folded
                p[e] = ((mword >> e) & 1u) ? pe : 0.f;
            }
            union { bf16x8 v; __hip_bfloat162 h2[4]; } u;
#pragma unroll
            for (int e2 = 0; e2 < 4; e2++)
                u.h2[e2] = __float22bfloat162_rn(
                    make_float2(p[2 * e2], p[2 * e2 + 1]));
            afr[mw] = u.v;
        }
        // ---- MFMAs ----
#pragma unroll
        for (int ct = 0; ct < CTT; ct++)
#pragma unroll
            for (int mw = 0; mw < MW; mw++)
                acc[mw][ct] = __builtin_amdgcn_mfma_f32_16x16x32_bf16(
                    afr[mw], bfrag[ct], acc[mw][ct], 0, 0, 0);
#pragma unroll
        for (int mw = 0; mw < MW; mw++)
            sac[mw] = __builtin_amdgcn_mfma_f32_16x16x32_bf16(
                afr[mw], ones, sac[mw], 0, 0, 0);
    }

    // ---- epilogue ----
#pragma unroll
    for (int rd = 0; rd < CTT / CC; rd++) {
#pragma unroll
        for (int mw = 0; mw < MW; mw++) {
#pragma unroll
            for (int cc = 0; cc < CC; cc++) {
#pragma unroll
                for (int r = 0; r < 4; r++)
                    sh[(((mw * G + g) * 16 + quad * 4 + r) * CC + cc) * 17 + m] =
                        acc[mw][rd * CC + cc][r];
            }
            if (rd == 0 && m == 0) {
#pragma unroll
                for (int r = 0; r < 4; r++)
                    dsh[(mw * G + g) * 16 + quad * 4 + r] = sac[mw][r];
            }
        }
        __syncthreads();
        if (t < 16 * CC * 16) {
            int row, chl;
            if (D == 64) { row = t & 15; chl = (t >> 4) & 15; }
            else         { chl = t & 31; row = (t >> 5) & 15; }
#pragma unroll
            for (int mw = 0; mw < MW; mw++) {
                float av = 0.f, ss = 0.f;
#pragma unroll
                for (int gg = 0; gg < G; gg++) {
                    av += sh[(((mw * G + gg) * 16 + row) * CC + (chl >> 4)) * 17 +
                             (chl & 15)];
                    ss += dsh[(mw * G + gg) * 16 + row];
                }
                float v = av / ss;
                v = (v > 0.f) ? v : (__builtin_amdgcn_exp2f(v * LOG2E) - 1.f);
                const int chg = h * D + slc * (CTT * 16) + rd * CC * 16 + chl;
                const int irow = i0 + mw * 16 + row;
                if (D == 64)
                    outp[(size_t)irow * (NHEADS * HID) + chg] = v;  // h1[i][ch]
                else
                    outp[(size_t)irow * D + chg] = v;               // out[i][ch]
            }
        }
        __syncthreads();
    }
    }  // rep
}

// ---------------------------------------------------------------------------
// gemm2 via MFMA bf16-split, REP-doubled for probe.
// ---------------------------------------------------------------------------
__global__ __launch_bounds__(512, 2) void gemm2_kernel(
        const float* __restrict__ h1, const float* __restrict__ W2,
        const float* __restrict__ a2, __hip_bfloat16* __restrict__ WhB2,
        float* __restrict__ f1, float* __restrict__ f2) {
    __shared__ float fred[8][16][2];
    const int t = threadIdx.x;
    const int w = t >> 6, lane = t & 63, m = lane & 15, quad = lane >> 4;
    const int i0 = blockIdx.x * 16;
    const float* arow = h1 + (size_t)(i0 + m) * IN_DIM;
    const float* wp = W2 + w * 16 + m;
    for (int rep = 0; rep < REP; rep++) {
    const f32x4 zero = {0.f, 0.f, 0.f, 0.f};
    f32x4 acc = zero;
    for (int ks = 0; ks < 8; ks++) {
        const int kb = ks * 32 + quad * 8;
        const float4 xa = *(const float4*)(arow + kb);
        const float4 xb = *(const float4*)(arow + kb + 4);
        const float xf[8] = {xa.x, xa.y, xa.z, xa.w, xb.x, xb.y, xb.z, xb.w};
        bf16x8 xh, xl, wh, wl;
#pragma unroll
        for (int e = 0; e < 8; e++) {
            const ushort2 s = bsplit(xf[e]);
            xh[e] = (short)s.x; xl[e] = (short)s.y;
        }
#pragma unroll
        for (int e = 0; e < 8; e++) {
            const ushort2 s = bsplit(wp[(size_t)(kb + e) * OUT_DIM]);
            wh[e] = (short)s.x; wl[e] = (short)s.y;
        }
        acc = __builtin_amdgcn_mfma_f32_16x16x32_bf16(xh, wh, acc, 0, 0, 0);
        acc = __builtin_amdgcn_mfma_f32_16x16x32_bf16(xl, wh, acc, 0, 0, 0);
        acc = __builtin_amdgcn_mfma_f32_16x16x32_bf16(xh, wl, acc, 0, 0, 0);
    }
    const int jblk = i0 >> 5, jb2 = (i0 >> 4) & 1;
#pragma unroll
    for (int r = 0; r < 4; r++) {
        const int jo = quad * 4 + r;
        const int lane_idx = m + 16 * (2 * jb2 + (jo >> 3));
        WhB2[(((size_t)jblk * 8 + w) * 64 + lane_idx) * 8 + (jo & 7)] =
            __float2bfloat16(acc[r]);
    }
    const float av1 = a2[w * 16 + m], av2 = a2[OUT_DIM + w * 16 + m];
    float s1[4], s2[4];
#pragma unroll
    for (int r = 0; r < 4; r++) { s1[r] = acc[r] * av1; s2[r] = acc[r] * av2; }
#pragma unroll
    for (int mm = 8; mm > 0; mm >>= 1) {
#pragma unroll
        for (int r = 0; r < 4; r++) {
            s1[r] += __shfl_xor(s1[r], mm, 64);
            s2[r] += __shfl_xor(s2[r], mm, 64);
        }
    }
    if (m == 0) {
#pragma unroll
        for (int r = 0; r < 4; r++) {
            fred[w][quad * 4 + r][0] = s1[r];
            fred[w][quad * 4 + r][1] = s2[r];
        }
    }
    __syncthreads();
    if (t < 32) {
        const int row = t & 15, fn = t >> 4;
        float s = 0.f;
#pragma unroll
        for (int w8 = 0; w8 < 8; w8++) s += fred[w8][row][fn];
        (fn ? f2 : f1)[i0 + row] = s * LOG2E;
    }
    __syncthreads();   // protect fred before next rep's writes
    }  // rep
}

// ---------------------------------------------------------------------------
extern "C" void kernel_launch(void* const* d_in, const int* in_sizes, int n_in,
                              void* d_out, int out_size, void* d_ws, size_t ws_size,
                              hipStream_t stream) {
    const float* x   = (const float*)d_in[0];
    const int*   adj = (const int*)d_in[1];
    const float* Wh_ = (const float*)d_in[2];
    const float* ah  = (const float*)d_in[3];
    const float* W2  = (const float*)d_in[4];
    const float* a2  = (const float*)d_in[5];
    float* out = (float*)d_out;

    float* ws = (float*)d_ws;
    float* f1a = ws;                                    // 4*N
    float* f2a = f1a + (size_t)NHEADS * N;              // 4*N
    float* f1b = f2a + (size_t)NHEADS * N;              // N
    float* f2b = f1b + N;                               // N
    float* h1  = f2b + N;                               // N*256 fp32 (4MB)
    __hip_bfloat16* WhB1 = (__hip_bfloat16*)(h1 + (size_t)IN_DIM * N);  // 2MB
    __hip_bfloat16* WhB2 = WhB1 + (size_t)NHEADS * HID * N;            // 1MB
    unsigned* maskT = (unsigned*)(WhB2 + (size_t)OUT_DIM * N);         // 2MB

    prep_kernel<<<1280, 256, 0, stream>>>(x, Wh_, ah, adj, WhB1, f1a, f2a, maskT);
    attn_fused<NHEADS, HID, 1, 8, 2>
        <<<dim3(N / 32, NHEADS), 512, 0, stream>>>(maskT, WhB1, f1a, f2a, h1);
    gemm2_kernel<<<N / 16, 512, 0, stream>>>(h1, W2, a2, WhB2, f1b, f2b);
    attn_fused<1, OUT_DIM, 2, 8, 1>
        <<<dim3(N / 16, 2), 512, 0, stream>>>(maskT, WhB2, f1b, f2b, out);
}

// Round 7
// 166.142 us; speedup vs baseline: 1.3449x; 1.3449x over previous
//
#include <hip/hip_runtime.h>
#include <hip/hip_bf16.h>

#define N 4096
#define IN_DIM 256
#define HID 64
#define NHEADS 4
#define OUT_DIM 128
#define LOG2E 1.44269504088896340736f

typedef __attribute__((ext_vector_type(8))) short bf16x8;
typedef __attribute__((ext_vector_type(4))) float f32x4;

// Two-term bf16 split: v ~= hi + lo with |err| ~ 2^-17 |v|.
__device__ __forceinline__ ushort2 bsplit(float v) {
    const ushort h = __hip_bfloat16_raw(__float2bfloat16(v)).x;
    const float vh = __uint_as_float((unsigned)h << 16);
    const ushort l = __hip_bfloat16_raw(__float2bfloat16(v - vh)).x;
    return make_ushort2(h, l);
}

// ---------------------------------------------------------------------------
// prep_kernel = gemm1-MFMA (blocks 0..255) + mask pack (blocks 256..1279).
// ---------------------------------------------------------------------------
__global__ __launch_bounds__(256, 4) void prep_kernel(
        const float* __restrict__ x, const float* __restrict__ W,
        const float* __restrict__ a, const int* __restrict__ adj,
        __hip_bfloat16* __restrict__ WhB,
        float* __restrict__ f1, float* __restrict__ f2,
        unsigned* __restrict__ maskT) {
    const int t = threadIdx.x;
    if (blockIdx.x < 256) {
        // ---------------- gemm1 via MFMA ----------------
        const int h = t >> 6, lane = t & 63, m = lane & 15, quad = lane >> 4;
        const int i0 = blockIdx.x * 16;
        const float* xrow = x + (size_t)(i0 + m) * IN_DIM;
        const float* Wp = W + (size_t)h * IN_DIM * HID;
        const f32x4 zero = {0.f, 0.f, 0.f, 0.f};
        f32x4 acc[4] = {zero, zero, zero, zero};
        for (int ks = 0; ks < 8; ks++) {
            const int kb = ks * 32 + quad * 8;
            const float4 xa = *(const float4*)(xrow + kb);
            const float4 xb = *(const float4*)(xrow + kb + 4);
            const float xf[8] = {xa.x, xa.y, xa.z, xa.w, xb.x, xb.y, xb.z, xb.w};
            bf16x8 xh, xl;
#pragma unroll
            for (int e = 0; e < 8; e++) {
                const ushort2 s = bsplit(xf[e]);
                xh[e] = (short)s.x; xl[e] = (short)s.y;
            }
#pragma unroll
            for (int ct = 0; ct < 4; ct++) {
                bf16x8 wh, wl;
#pragma unroll
                for (int e = 0; e < 8; e++) {
                    const ushort2 s =
                        bsplit(Wp[(size_t)(kb + e) * HID + ct * 16 + m]);
                    wh[e] = (short)s.x; wl[e] = (short)s.y;
                }
                acc[ct] = __builtin_amdgcn_mfma_f32_16x16x32_bf16(
                    xh, wh, acc[ct], 0, 0, 0);
                acc[ct] = __builtin_amdgcn_mfma_f32_16x16x32_bf16(
                    xl, wh, acc[ct], 0, 0, 0);
                acc[ct] = __builtin_amdgcn_mfma_f32_16x16x32_bf16(
                    xh, wl, acc[ct], 0, 0, 0);
            }
        }
        // ---- WhB1 frag store: j = i0+quad*4+r, c = ct*16+m ----
        const int jblk = i0 >> 5, jb2 = (i0 >> 4) & 1;
#pragma unroll
        for (int ct = 0; ct < 4; ct++) {
#pragma unroll
            for (int r = 0; r < 4; r++) {
                const int jo = quad * 4 + r;
                const int lane_idx = m + 16 * (2 * jb2 + (jo >> 3));
                WhB[((((size_t)h * (N / 32) + jblk) * 4 + ct) * 64 + lane_idx) *
                        8 + (jo & 7)] = __float2bfloat16(acc[ct][r]);
            }
        }
        // ---- f1/f2 ----
        float av1[4], av2[4];
#pragma unroll
        for (int ct = 0; ct < 4; ct++) {
            av1[ct] = a[h * 2 * HID + ct * 16 + m];
            av2[ct] = a[h * 2 * HID + HID + ct * 16 + m];
        }
        float s1[4], s2[4];
#pragma unroll
        for (int r = 0; r < 4; r++) {
            s1[r] = 0.f; s2[r] = 0.f;
#pragma unroll
            for (int ct = 0; ct < 4; ct++) {
                s1[r] += acc[ct][r] * av1[ct];
                s2[r] += acc[ct][r] * av2[ct];
            }
        }
#pragma unroll
        for (int mm = 8; mm > 0; mm >>= 1) {
#pragma unroll
            for (int r = 0; r < 4; r++) {
                s1[r] += __shfl_xor(s1[r], mm, 64);
                s2[r] += __shfl_xor(s2[r], mm, 64);
            }
        }
        if (m == 0) {
#pragma unroll
            for (int r = 0; r < 4; r++) {
                f1[(size_t)h * N + i0 + quad * 4 + r] = s1[r] * LOG2E;
                f2[(size_t)h * N + i0 + quad * 4 + r] = s2[r] * LOG2E;
            }
        }
    } else {
        // ---------------- mask pack (bit-spread, verified R6) ----------------
        const int lane = t & 63, w = t >> 6;
        const int i = (blockIdx.x - 256) * 4 + w;      // one row per wave
        const int4* arow = (const int4*)(adj + (size_t)i * N);
        for (int jb = 0; jb < N / 256; jb++) {
            const int4 a4 = arow[jb * 64 + lane];
            unsigned long long bal[4];
            bal[0] = __ballot(a4.x > 0);
            bal[1] = __ballot(a4.y > 0);
            bal[2] = __ballot(a4.z > 0);
            bal[3] = __ballot(a4.w > 0);
            if (lane < 8) {
                unsigned word = 0;
#pragma unroll
                for (int e = 0; e < 4; e++) {
                    unsigned xv = (unsigned)(bal[e] >> (8 * lane)) & 0xFFu;
                    xv = (xv | (xv << 12)) & 0x000F000Fu;
                    xv = (xv | (xv << 6))  & 0x03030303u;
                    xv = (xv | (xv << 3))  & 0x11111111u;
                    word |= xv << e;
                }
                maskT[(size_t)(jb * 8 + lane) * N + i] = word;
            }
        }
    }
}

// ---------------------------------------------------------------------------
// Fused attention layer, R7: (a) __launch_bounds__(...,2) -> 256-VGPR cap
// (grid already only fills 2 blocks/CU, so no occupancy cost); (b) K-loop
// addressing strength-reduced to pointer increments; (c) mask applied as a
// bitwise AND on packed bf16 pairs via multiply-spread (mword*0x8001;
// halfword-replicate *0xFFFF) -- bit-exact vs cndmask, fewer VALU ops.
// L1: HEADS=4, DSL=1, MW=2, G=8 -> grid (128,4)=512 blocks, 512 thr.
// L2: HEADS=1, DSL=1, MW=1, G=8 -> grid (256,1)=256 blocks (P computed once).
// ---------------------------------------------------------------------------
template <int HEADS, int D, int DSL, int G, int MW>
__global__ __launch_bounds__(G * 64, 2) void attn_fused(
        const unsigned* __restrict__ maskT,             // [N/32][N]
        const __hip_bfloat16* __restrict__ WhB,          // [H][N/32][D/16][64][8]
        const float* __restrict__ f1g, const float* __restrict__ f2g,
        float* __restrict__ outp) {
    constexpr int CTtot = D / 16;
    constexpr int CTT = CTtot / DSL;
    constexpr int CC = (D == 64) ? 1 : 2;
    constexpr int KSTEPS = N / (32 * G);
    __shared__ float sh[MW * G * 16 * CC * 17];
    __shared__ float dsh[MW * G * 16];
    const int t = threadIdx.x;
    const int g = t >> 6, lane = t & 63;
    const int m = lane & 15, quad = lane >> 4;
    const int h = blockIdx.y / DSL, slc = blockIdx.y % DSL;
    const int i0 = blockIdx.x * (16 * MW);

    float f1v[MW];
#pragma unroll
    for (int mw = 0; mw < MW; mw++)
        f1v[mw] = f1g[(size_t)h * N + i0 + mw * 16 + m];

    // strength-reduced stream pointers
    const unsigned* mp = maskT + (size_t)(g * KSTEPS) * N + i0 + m;
    const float* fp = f2g + (size_t)h * N + g * (N / G) + quad * 8;
    const bf16x8* bp = (const bf16x8*)WhB +
                       ((size_t)h * (N / 32) * CTtot +
                        (size_t)(g * KSTEPS) * CTtot + slc * CTT) * 64 + lane;

    const f32x4 zero = {0.f, 0.f, 0.f, 0.f};
    f32x4 acc[MW][CTT];
    f32x4 sac[MW];
#pragma unroll
    for (int mw = 0; mw < MW; mw++) {
        sac[mw] = zero;
#pragma unroll
        for (int ct = 0; ct < CTT; ct++) acc[mw][ct] = zero;
    }
    const short one_bf = (short)0x3F80;
    const bf16x8 ones = {one_bf, one_bf, one_bf, one_bf,
                         one_bf, one_bf, one_bf, one_bf};

    unsigned mwrd[2][MW];
    float4 f2lo[2], f2hi[2];
    auto stage = [&](int b) {
#pragma unroll
        for (int mw = 0; mw < MW; mw++) mwrd[b][mw] = mp[mw * 16];
        f2lo[b] = *(const float4*)(fp);
        f2hi[b] = *(const float4*)(fp + 4);
    };

    stage(0); mp += N; fp += 32;
#pragma unroll 2
    for (int ks = 0; ks < KSTEPS; ks++) {
        const int cur = ks & 1;
        // ---- current-step B frags (latency hidden under P-gen) ----
        bf16x8 bfrag[CTT];
#pragma unroll
        for (int ct = 0; ct < CTT; ct++) bfrag[ct] = bp[ct * 64];
        bp += CTtot * 64;
        if (ks + 1 < KSTEPS) { stage(cur ^ 1); mp += N; fp += 32; }
        // ---- P-gen ----
        const float fe[8] = {f2lo[cur].x, f2lo[cur].y, f2lo[cur].z, f2lo[cur].w,
                             f2hi[cur].x, f2hi[cur].y, f2hi[cur].z, f2hi[cur].w};
        bf16x8 afr[MW];
#pragma unroll
        for (int mw = 0; mw < MW; mw++) {
            const unsigned mword = (mwrd[cur][mw] >> (quad * 8)) & 0xFFu;
            const unsigned spread = mword * 0x8001u;   // b_e at bit e and e+15
            float p[8];
#pragma unroll
            for (int e = 0; e < 8; e++) {
                const float tt = f1v[mw] + fe[e];
                const float lr = fmaxf(tt, 0.5f * tt);        // LeakyReLU(0.5)
                p[e] = __builtin_amdgcn_exp2f(lr);            // log2e folded
            }
            union { bf16x8 v; unsigned u32[4]; __hip_bfloat162 h2[4]; } u;
#pragma unroll
            for (int e2 = 0; e2 < 4; e2++) {
                u.h2[e2] = __float22bfloat162_rn(
                    make_float2(p[2 * e2], p[2 * e2 + 1]));
                const unsigned mk =
                    ((spread >> (2 * e2)) & 0x00010001u) * 0xFFFFu;
                u.u32[e2] &= mk;                               // bf16 mask-AND
            }
            afr[mw] = u.v;
        }
        // ---- MFMAs (B amortized across MW row-tiles) ----
#pragma unroll
        for (int ct = 0; ct < CTT; ct++)
#pragma unroll
            for (int mw = 0; mw < MW; mw++)
                acc[mw][ct] = __builtin_amdgcn_mfma_f32_16x16x32_bf16(
                    afr[mw], bfrag[ct], acc[mw][ct], 0, 0, 0);
#pragma unroll
        for (int mw = 0; mw < MW; mw++)
            sac[mw] = __builtin_amdgcn_mfma_f32_16x16x32_bf16(
                afr[mw], ones, sac[mw], 0, 0, 0);
    }

    // ---- epilogue: LDS cross-group reduction, CC ct-tiles per round ----
#pragma unroll
    for (int rd = 0; rd < CTT / CC; rd++) {
#pragma unroll
        for (int mw = 0; mw < MW; mw++) {
#pragma unroll
            for (int cc = 0; cc < CC; cc++) {
#pragma unroll
                for (int r = 0; r < 4; r++)
                    sh[(((mw * G + g) * 16 + quad * 4 + r) * CC + cc) * 17 + m] =
                        acc[mw][rd * CC + cc][r];
            }
            if (rd == 0 && m == 0) {
#pragma unroll
                for (int r = 0; r < 4; r++)
                    dsh[(mw * G + g) * 16 + quad * 4 + r] = sac[mw][r];
            }
        }
        __syncthreads();
        if (t < 16 * CC * 16) {
            int row, chl;
            if (D == 64) { row = t & 15; chl = (t >> 4) & 15; }
            else         { chl = t & 31; row = (t >> 5) & 15; }
#pragma unroll
            for (int mw = 0; mw < MW; mw++) {
                float av = 0.f, ss = 0.f;
#pragma unroll
                for (int gg = 0; gg < G; gg++) {
                    av += sh[(((mw * G + gg) * 16 + row) * CC + (chl >> 4)) * 17 +
                             (chl & 15)];
                    ss += dsh[(mw * G + gg) * 16 + row];
                }
                float v = av / ss;
                v = (v > 0.f) ? v : (__builtin_amdgcn_exp2f(v * LOG2E) - 1.f);
                const int chg = h * D + slc * (CTT * 16) + rd * CC * 16 + chl;
                const int irow = i0 + mw * 16 + row;
                if (D == 64)
                    outp[(size_t)irow * (NHEADS * HID) + chg] = v;  // h1[i][ch]
                else
                    outp[(size_t)irow * D + chg] = v;               // out[i][ch]
            }
        }
        __syncthreads();
    }
}

// ---------------------------------------------------------------------------
// gemm2 via MFMA bf16-split: h1[4096][256] @ W2[256][128].
// ---------------------------------------------------------------------------
__global__ __launch_bounds__(512, 2) void gemm2_kernel(
        const float* __restrict__ h1, const float* __restrict__ W2,
        const float* __restrict__ a2, __hip_bfloat16* __restrict__ WhB2,
        float* __restrict__ f1, float* __restrict__ f2) {
    __shared__ float fred[8][16][2];
    const int t = threadIdx.x;
    const int w = t >> 6, lane = t & 63, m = lane & 15, quad = lane >> 4;
    const int i0 = blockIdx.x * 16;
    const float* arow = h1 + (size_t)(i0 + m) * IN_DIM;
    const float* wp = W2 + w * 16 + m;
    const f32x4 zero = {0.f, 0.f, 0.f, 0.f};
    f32x4 acc = zero;
    for (int ks = 0; ks < 8; ks++) {
        const int kb = ks * 32 + quad * 8;
        const float4 xa = *(const float4*)(arow + kb);
        const float4 xb = *(const float4*)(arow + kb + 4);
        const float xf[8] = {xa.x, xa.y, xa.z, xa.w, xb.x, xb.y, xb.z, xb.w};
        bf16x8 xh, xl, wh, wl;
#pragma unroll
        for (int e = 0; e < 8; e++) {
            const ushort2 s = bsplit(xf[e]);
            xh[e] = (short)s.x; xl[e] = (short)s.y;
        }
#pragma unroll
        for (int e = 0; e < 8; e++) {
            const ushort2 s = bsplit(wp[(size_t)(kb + e) * OUT_DIM]);
            wh[e] = (short)s.x; wl[e] = (short)s.y;
        }
        acc = __builtin_amdgcn_mfma_f32_16x16x32_bf16(xh, wh, acc, 0, 0, 0);
        acc = __builtin_amdgcn_mfma_f32_16x16x32_bf16(xl, wh, acc, 0, 0, 0);
        acc = __builtin_amdgcn_mfma_f32_16x16x32_bf16(xh, wl, acc, 0, 0, 0);
    }
    const int jblk = i0 >> 5, jb2 = (i0 >> 4) & 1;
#pragma unroll
    for (int r = 0; r < 4; r++) {
        const int jo = quad * 4 + r;
        const int lane_idx = m + 16 * (2 * jb2 + (jo >> 3));
        WhB2[(((size_t)jblk * 8 + w) * 64 + lane_idx) * 8 + (jo & 7)] =
            __float2bfloat16(acc[r]);
    }
    const float av1 = a2[w * 16 + m], av2 = a2[OUT_DIM + w * 16 + m];
    float s1[4], s2[4];
#pragma unroll
    for (int r = 0; r < 4; r++) { s1[r] = acc[r] * av1; s2[r] = acc[r] * av2; }
#pragma unroll
    for (int mm = 8; mm > 0; mm >>= 1) {
#pragma unroll
        for (int r = 0; r < 4; r++) {
            s1[r] += __shfl_xor(s1[r], mm, 64);
            s2[r] += __shfl_xor(s2[r], mm, 64);
        }
    }
    if (m == 0) {
#pragma unroll
        for (int r = 0; r < 4; r++) {
            fred[w][quad * 4 + r][0] = s1[r];
            fred[w][quad * 4 + r][1] = s2[r];
        }
    }
    __syncthreads();
    if (t < 32) {
        const int row = t & 15, fn = t >> 4;
        float s = 0.f;
#pragma unroll
        for (int w8 = 0; w8 < 8; w8++) s += fred[w8][row][fn];
        (fn ? f2 : f1)[i0 + row] = s * LOG2E;
    }
}

// ---------------------------------------------------------------------------
extern "C" void kernel_launch(void* const* d_in, const int* in_sizes, int n_in,
                              void* d_out, int out_size, void* d_ws, size_t ws_size,
                              hipStream_t stream) {
    const float* x   = (const float*)d_in[0];
    const int*   adj = (const int*)d_in[1];
    const float* Wh_ = (const float*)d_in[2];
    const float* ah  = (const float*)d_in[3];
    const float* W2  = (const float*)d_in[4];
    const float* a2  = (const float*)d_in[5];
    float* out = (float*)d_out;

    float* ws = (float*)d_ws;
    float* f1a = ws;                                    // 4*N
    float* f2a = f1a + (size_t)NHEADS * N;              // 4*N
    float* f1b = f2a + (size_t)NHEADS * N;              // N
    float* f2b = f1b + N;                               // N
    float* h1  = f2b + N;                               // N*256 fp32 (4MB)
    __hip_bfloat16* WhB1 = (__hip_bfloat16*)(h1 + (size_t)IN_DIM * N);  // 2MB
    __hip_bfloat16* WhB2 = WhB1 + (size_t)NHEADS * HID * N;            // 1MB
    unsigned* maskT = (unsigned*)(WhB2 + (size_t)OUT_DIM * N);         // 2MB

    prep_kernel<<<1280, 256, 0, stream>>>(x, Wh_, ah, adj, WhB1, f1a, f2a, maskT);
    attn_fused<NHEADS, HID, 1, 8, 2>
        <<<dim3(N / 32, NHEADS), 512, 0, stream>>>(maskT, WhB1, f1a, f2a, h1);
    gemm2_kernel<<<N / 16, 512, 0, stream>>>(h1, W2, a2, WhB2, f1b, f2b);
    attn_fused<1, OUT_DIM, 1, 8, 1>
        <<<dim3(N / 16, 1), 512, 0, stream>>>(maskT, WhB2, f1b, f2b, out);
}